// Round 9
// baseline (69.206 us; speedup 1.0000x reference)
//
#include <hip/hip_runtime.h>
#include <hip/hip_bf16.h>
#include <math.h>

// Problem constants
#define B_  8
#define T_  2048
#define C_  128
#define H_  4
#define DH_ 32
#define BH_ 32
#define NTOK 16384
// (1/sqrt(32)) * log2(e): scores come out in log2 domain -> softmax via exp2
#define QSCALE_ 0.25503486f

typedef __attribute__((ext_vector_type(8))) __bf16 bfrag;        // 4 VGPRs, MFMA A/B
typedef __attribute__((ext_vector_type(4))) float f32x4;
typedef __attribute__((ext_vector_type(16))) float f32x16;       // 32x32 MFMA C/D
typedef __attribute__((ext_vector_type(2))) unsigned int u32x2;
typedef __attribute__((ext_vector_type(4))) unsigned int u32x4;

__device__ __forceinline__ unsigned int pack2bf(float a, float b) {
    unsigned int ua = __float_as_uint(a);
    unsigned int ub = __float_as_uint(b);
    ua += 0x7fffu + ((ua >> 16) & 1u);   // RNE to bf16
    ub += 0x7fffu + ((ub >> 16) & 1u);
    return (ua >> 16) | (ub & 0xffff0000u);
}

// single-instruction packed f32x2 -> bf16x2 (RNE; no builtin on gfx950)
__device__ __forceinline__ unsigned int cvtpk_bf16(float lo, float hi) {
    unsigned int r;
    asm("v_cvt_pk_bf16_f32 %0, %1, %2" : "=v"(r) : "v"(lo), "v"(hi));
    return r;
}

// raw v_exp_f32 (2^x)
__device__ __forceinline__ float fast_exp2(float x) {
    float r;
    asm("v_exp_f32 %0, %1" : "=v"(r) : "v"(x));
    return r;
}

// ---------------------------------------------------------------------------
// Kernel 0: prep — transpose Wqkv -> WqkvT bf16 [384][128]; Wout -> WoutT
// bf16 [128][128]. (x cast is folded into qkv_mfma now.) 32 blocks.
// ---------------------------------------------------------------------------
__global__ __launch_bounds__(256)
void prep(const float* __restrict__ Wqkv, const float* __restrict__ Wout,
          __hip_bfloat16* __restrict__ WqkvT, __hip_bfloat16* __restrict__ WoutT) {
    const int bid = blockIdx.x;
    const int tid = threadIdx.x;
    if (bid < 24) {
        const int idx = bid * 256 + tid;             // 0..6143
        const int n = idx >> 4, k8 = idx & 15;
        float v[8];
#pragma unroll
        for (int i = 0; i < 8; ++i) v[i] = Wqkv[(k8 * 8 + i) * 384 + n];
        u32x4 pk;
        pk.x = pack2bf(v[0], v[1]); pk.y = pack2bf(v[2], v[3]);
        pk.z = pack2bf(v[4], v[5]); pk.w = pack2bf(v[6], v[7]);
        *(u32x4*)(WqkvT + n * 128 + k8 * 8) = pk;
    } else {
        const int idx = (bid - 24) * 256 + tid;      // 0..2047
        const int n = idx >> 4, k8 = idx & 15;
        float v[8];
#pragma unroll
        for (int i = 0; i < 8; ++i) v[i] = Wout[(k8 * 8 + i) * 128 + n];
        u32x4 pk;
        pk.x = pack2bf(v[0], v[1]); pk.y = pack2bf(v[2], v[3]);
        pk.z = pack2bf(v[4], v[5]); pk.w = pack2bf(v[6], v[7]);
        *(u32x4*)(WoutT + n * 128 + k8 * 8) = pk;
    }
}

// ---------------------------------------------------------------------------
// Kernel 1: MFMA QKV projection; reads fp32 x directly (cvt_pk to bf16 frags).
// Q/K (j<4): swapped mfma(wf,xf) -> lane owns token, regs = 4 consecutive
//   cols -> one 8B store per j. V (j>=4): mfma(xf,wf) -> lane owns col d,
//   regs = 4 consecutive tokens -> one 8B store into Vt[d][t].
// ---------------------------------------------------------------------------
__global__ __launch_bounds__(256)
void qkv_mfma(const float* __restrict__ x,
              const __hip_bfloat16* __restrict__ WT,
              const float* __restrict__ bqkv,
              __hip_bfloat16* __restrict__ Qb, __hip_bfloat16* __restrict__ Kb,
              __hip_bfloat16* __restrict__ Vt) {
    const int mbase = blockIdx.x * 16;
    const int w = threadIdx.x >> 6, lane = threadIdx.x & 63;
    const int qi = lane & 15, grp = lane >> 4;

    const f32x4 zero = {0.f, 0.f, 0.f, 0.f};
    f32x4 acc[6] = {zero, zero, zero, zero, zero, zero};

    const float* xrow = x + (size_t)(mbase + qi) * 128;
    bfrag xf[4];
#pragma unroll
    for (int ks = 0; ks < 4; ++ks) {
        const float4 a = *(const float4*)(xrow + ks * 32 + grp * 8);
        const float4 b = *(const float4*)(xrow + ks * 32 + grp * 8 + 4);
        u32x4 pk;
        pk.x = cvtpk_bf16(a.x, a.y);
        pk.y = cvtpk_bf16(a.z, a.w);
        pk.z = cvtpk_bf16(b.x, b.y);
        pk.w = cvtpk_bf16(b.z, b.w);
        xf[ks] = __builtin_bit_cast(bfrag, pk);
    }

#pragma unroll
    for (int j = 0; j < 6; ++j) {
        const int nb = j * 4 + w;
#pragma unroll
        for (int ks = 0; ks < 4; ++ks) {
            const bfrag wf = *(const bfrag*)(WT + (size_t)(nb * 16 + qi) * 128 + ks * 32 + grp * 8);
            if (j < 4) acc[j] = __builtin_amdgcn_mfma_f32_16x16x32_bf16(wf, xf[ks], acc[j], 0, 0, 0);
            else       acc[j] = __builtin_amdgcn_mfma_f32_16x16x32_bf16(xf[ks], wf, acc[j], 0, 0, 0);
        }
    }

    const long bb = mbase >> 11;        // batch
    const long tloc = mbase & 2047;     // token within batch

    // Q/K: lane owns token t = tloc+qi, regs are cols c0..c0+3
#pragma unroll
    for (int j = 0; j < 4; ++j) {
        const int nb = j * 4 + w;
        const int c0 = nb * 16 + grp * 4;
        const float4 bias = *(const float4*)&bqkv[c0];
        const int local = c0 & 127;
        const int h = local >> 5, d0 = local & 31;
        __hip_bfloat16* dst = (j < 2) ? Qb : Kb;
        const float sc = (j < 2) ? QSCALE_ : 1.f;
        const long t = tloc + qi;
        u32x2 pw;
        pw.x = pack2bf((acc[j][0] + bias.x) * sc, (acc[j][1] + bias.y) * sc);
        pw.y = pack2bf((acc[j][2] + bias.z) * sc, (acc[j][3] + bias.w) * sc);
        *(u32x2*)&dst[((bb * H_ + h) * T_ + t) * DH_ + d0] = pw;
    }
    // V: lane owns col c, regs are tokens tloc+grp*4 .. +3
#pragma unroll
    for (int j = 4; j < 6; ++j) {
        const int nb = j * 4 + w;
        const int c = nb * 16 + qi;
        const int local = c - 256;
        const int h = local >> 5, d = local & 31;
        const float bias = bqkv[c];
        u32x2 pw;
        pw.x = pack2bf(acc[j][0] + bias, acc[j][1] + bias);
        pw.y = pack2bf(acc[j][2] + bias, acc[j][3] + bias);
        *(u32x2*)&Vt[((bb * H_ + h) * DH_ + d) * T_ + tloc + grp * 4] = pw;
    }
}

// ---------------------------------------------------------------------------
// Kernel 2: flash attention, 32x32x16 MFMA, in-register P path.
// ONE 32-q chunk per block (grid 2048 = 8 xcd x 4 bh x 64 chunks, big chunks
// first). 4 waves split the (c+1) 32-s units round-robin; band only at u==c.
// exp2 in-place, zero-C per unit, 2-deep ping-pong prefetch. Slim state ->
// __launch_bounds__(256,4) for 4 waves/SIMD. One LDS combine phase.
// ---------------------------------------------------------------------------
__global__ __launch_bounds__(256, 4)
void attn_mfma(const __hip_bfloat16* __restrict__ Qb,
               const __hip_bfloat16* __restrict__ Kb,
               const __hip_bfloat16* __restrict__ Vt,
               __hip_bfloat16* __restrict__ Ob) {
    __shared__ float csm[4 * 64 * 17];    // 17.4 KB combine buffer

    const int lin  = blockIdx.x;          // 0..2047
    const int xcd  = lin & 7;
    const int slot = lin >> 3;            // 0..255
    const int bh   = (xcd << 2) | (slot & 3);
    const int c    = 63 - (slot >> 2);    // chunk 0..63, heavy chunks first
    const int b = bh >> 2, h = bh & 3;

    const int w    = threadIdx.x >> 6;
    const int lane = threadIdx.x & 63;
    const int ql   = lane & 31;
    const int hi   = lane >> 5;
    const int hi4  = hi * 4;
    const int hi8  = hi * 8;

    const int q = c * 32 + ql;

    const __hip_bfloat16* Qp = Qb + (size_t)bh * T_ * DH_;
    const __hip_bfloat16* Kp = Kb + (size_t)bh * T_ * DH_;
    const __hip_bfloat16* Vp = Vt + (size_t)bh * DH_ * T_;

    const bfrag qf0 = *(const bfrag*)(Qp + q * DH_ + hi8);
    const bfrag qf1 = *(const bfrag*)(Qp + q * DH_ + 16 + hi8);

    f32x16 o;
#pragma unroll
    for (int r = 0; r < 16; ++r) o[r] = 0.f;
    float l = 0.f;

    auto ldK = [&](int sbase, bfrag& k0, bfrag& k1, bfrag& v0, bfrag& v1) {
        k0 = *(const bfrag*)(Kp + (sbase + ql) * DH_ + hi8);
        k1 = *(const bfrag*)(Kp + (sbase + ql) * DH_ + 16 + hi8);
        v0 = *(const bfrag*)(Vp + ql * T_ + sbase + hi8);
        v1 = *(const bfrag*)(Vp + ql * T_ + sbase + 16 + hi8);
    };

    auto proc = [&](const bfrag& kf0, const bfrag& kf1, const bfrag& vf0,
                    const bfrag& vf1, int sbase, bool band) {
        f32x16 s;
#pragma unroll
        for (int r = 0; r < 16; ++r) s[r] = 0.f;
        s = __builtin_amdgcn_mfma_f32_32x32x16_bf16(kf0, qf0, s, 0, 0, 0);
        s = __builtin_amdgcn_mfma_f32_32x32x16_bf16(kf1, qf1, s, 0, 0, 0);
        if (band) {
#pragma unroll
            for (int r = 0; r < 16; ++r) {
                const int srow = sbase + (r & 3) + 8 * (r >> 2) + hi4;
                if (srow > q) s[r] = -INFINITY;
            }
        }
#pragma unroll
        for (int r = 0; r < 16; ++r) { s[r] = fast_exp2(s[r]); l += s[r]; }
        u32x4 w0, w1;
        {
            unsigned a0 = cvtpk_bf16(s[0], s[1]);
            unsigned a1 = cvtpk_bf16(s[2], s[3]);
            unsigned a2 = cvtpk_bf16(s[4], s[5]);
            unsigned a3 = cvtpk_bf16(s[6], s[7]);
            auto r02 = __builtin_amdgcn_permlane32_swap((int)a0, (int)a2, false, false);
            auto r13 = __builtin_amdgcn_permlane32_swap((int)a1, (int)a3, false, false);
            w0.x = (unsigned)r02[0]; w0.y = (unsigned)r13[0];
            w0.z = (unsigned)r02[1]; w0.w = (unsigned)r13[1];
        }
        {
            unsigned a0 = cvtpk_bf16(s[8],  s[9]);
            unsigned a1 = cvtpk_bf16(s[10], s[11]);
            unsigned a2 = cvtpk_bf16(s[12], s[13]);
            unsigned a3 = cvtpk_bf16(s[14], s[15]);
            auto r02 = __builtin_amdgcn_permlane32_swap((int)a0, (int)a2, false, false);
            auto r13 = __builtin_amdgcn_permlane32_swap((int)a1, (int)a3, false, false);
            w1.x = (unsigned)r02[0]; w1.y = (unsigned)r13[0];
            w1.z = (unsigned)r02[1]; w1.w = (unsigned)r13[1];
        }
        o = __builtin_amdgcn_mfma_f32_32x32x16_bf16(
                vf0, __builtin_bit_cast(bfrag, w0), o, 0, 0, 0);
        o = __builtin_amdgcn_mfma_f32_32x32x16_bf16(
                vf1, __builtin_bit_cast(bfrag, w1), o, 0, 0, 0);
    };

    // units u = w, w+4, ... <= c; unit u covers s in [32u, 32u+32)
    bfrag ck0, ck1, cv0, cv1, nk0, nk1, nv0, nv1;
    ldK(w * 32, ck0, ck1, cv0, cv1);     // harmless over-read if w > c

    for (int u = w; u <= c; u += 4) {
        if (u + 4 <= c) ldK((u + 4) * 32, nk0, nk1, nv0, nv1);
        proc(ck0, ck1, cv0, cv1, u * 32, u == c);
        ck0 = nk0; ck1 = nk1; cv0 = nv0; cv1 = nv1;
    }

    // merge the two hi-halves' l (same q, disjoint s rows)
    l += __shfl_xor(l, 32);

    // cross-wave combine
    float* my = csm + (w * 64 + lane) * 17;
    {
        f32x4 t0 = {o[0], o[1], o[2], o[3]};
        f32x4 t1 = {o[4], o[5], o[6], o[7]};
        f32x4 t2 = {o[8], o[9], o[10], o[11]};
        f32x4 t3 = {o[12], o[13], o[14], o[15]};
        *(f32x4*)(my + 0) = t0;  *(f32x4*)(my + 4) = t1;
        *(f32x4*)(my + 8) = t2;  *(f32x4*)(my + 12) = t3;
        my[16] = l;
    }
    __syncthreads();
    if (w == 0) {
#pragma unroll
        for (int ww = 1; ww < 4; ++ww) {
            const float* ov = csm + (ww * 64 + lane) * 17;
#pragma unroll
            for (int r = 0; r < 16; ++r) o[r] += ov[r];
            l += ov[16];
        }
        const float rl = 1.f / l;
        __hip_bfloat16* orow = Ob + ((size_t)b * T_ + q) * C_ + h * DH_;
#pragma unroll
        for (int g = 0; g < 4; ++g) {
            u32x2 pw;
            pw.x = pack2bf(o[g * 4 + 0] * rl, o[g * 4 + 1] * rl);
            pw.y = pack2bf(o[g * 4 + 2] * rl, o[g * 4 + 3] * rl);
            *(u32x2*)(orow + 8 * g + hi4) = pw;
        }
    }
}

// ---------------------------------------------------------------------------
// Kernel 3: MFMA output projection, swapped orientation -> float4 stores.
// ---------------------------------------------------------------------------
__global__ __launch_bounds__(256)
void out_mfma(const __hip_bfloat16* __restrict__ Ob,
              const __hip_bfloat16* __restrict__ WT,
              const float* __restrict__ bout, float* __restrict__ out) {
    const int mbase = blockIdx.x * 16;
    const int w = threadIdx.x >> 6, lane = threadIdx.x & 63;
    const int qi = lane & 15, grp = lane >> 4;

    const f32x4 zero = {0.f, 0.f, 0.f, 0.f};
    f32x4 acc[2] = {zero, zero};

    bfrag xf[4];
#pragma unroll
    for (int ks = 0; ks < 4; ++ks)
        xf[ks] = *(const bfrag*)(Ob + (size_t)(mbase + qi) * 128 + ks * 32 + grp * 8);

#pragma unroll
    for (int j = 0; j < 2; ++j) {
        const int nb = j * 4 + w;
#pragma unroll
        for (int ks = 0; ks < 4; ++ks) {
            const bfrag wf = *(const bfrag*)(WT + (size_t)(nb * 16 + qi) * 128 + ks * 32 + grp * 8);
            acc[j] = __builtin_amdgcn_mfma_f32_16x16x32_bf16(wf, xf[ks], acc[j], 0, 0, 0);
        }
    }

    const int row = mbase + qi;
#pragma unroll
    for (int j = 0; j < 2; ++j) {
        const int nb = j * 4 + w;
        const int c0 = nb * 16 + grp * 4;
        const float4 bias = *(const float4*)&bout[c0];
        float4 o;
        o.x = acc[j][0] + bias.x;  o.y = acc[j][1] + bias.y;
        o.z = acc[j][2] + bias.z;  o.w = acc[j][3] + bias.w;
        *(float4*)&out[(size_t)row * 128 + c0] = o;
    }
}

// ---------------------------------------------------------------------------
extern "C" void kernel_launch(void* const* d_in, const int* in_sizes, int n_in,
                              void* d_out, int out_size, void* d_ws, size_t ws_size,
                              hipStream_t stream) {
    const float* x    = (const float*)d_in[0];
    const float* Wqkv = (const float*)d_in[1];
    const float* bqkv = (const float*)d_in[2];
    const float* Wout = (const float*)d_in[3];
    const float* bout = (const float*)d_in[4];
    float* out = (float*)d_out;

    const size_t per = (size_t)BH_ * T_ * DH_;   // 2,097,152 bf16 elems = 4 MB
    __hip_bfloat16* Qb    = (__hip_bfloat16*)d_ws;
    __hip_bfloat16* Kb    = Qb + per;
    __hip_bfloat16* Vt    = Kb + per;
    __hip_bfloat16* Ob    = Vt + per;
    __hip_bfloat16* WqkvT = Ob + per;
    __hip_bfloat16* WoutT = WqkvT + 384 * 128;

    prep<<<32, 256, 0, stream>>>(Wqkv, Wout, WqkvT, WoutT);

    qkv_mfma<<<NTOK / 16, 256, 0, stream>>>(x, WqkvT, bqkv, Qb, Kb, Vt);

    attn_mfma<<<2048, 256, 0, stream>>>(Qb, Kb, Vt, Ob);

    out_mfma<<<NTOK / 16, 256, 0, stream>>>(Ob, WoutT, bout, out);
}